// Round 2
// baseline (100.538 us; speedup 1.0000x reference)
//
#include <hip/hip_runtime.h>
#include <math.h>

#define BROWS 16384
#define NCLASS 1000
#define NF4 250            // float4 chunks per row (1000/4)
#define IGNORE_INDEX (-100)

// One wave (64 lanes) per row. All three stage-rows are loaded up front as
// float4 (independent of the dependent target chain), then the three ranks
//   rank(t) = #{j: p[j] > p[t]} + #{j: p[j] == p[t] && j < t}
// are computed back-to-back entirely in registers. The x[t] broadcast is a
// uniform register select + __shfl instead of a dependent global load.
__global__ __launch_bounds__(256) void TopKBaseLoss_80281528697452_kernel(
    const float* __restrict__ x0,
    const float* __restrict__ x1,
    const float* __restrict__ x2,
    const int*   __restrict__ target,
    int*         __restrict__ out)
{
    const int gid  = blockIdx.x * blockDim.x + threadIdx.x;
    const int row  = gid >> 6;          // one wave per row
    const int lane = threadIdx.x & 63;
    if (row >= BROWS) return;

    const int t0 = target[row];         // uniform across the wave
    if (lane == 0) out[row] = t0;       // output 0: the original target

    const float4* __restrict__ r0 = (const float4*)(x0 + (long)row * NCLASS);
    const float4* __restrict__ r1 = (const float4*)(x1 + (long)row * NCLASS);
    const float4* __restrict__ r2 = (const float4*)(x2 + (long)row * NCLASS);

    const float NEG = -INFINITY;
    const float4 pad = make_float4(NEG, NEG, NEG, NEG);

    // 12 independent dwordx4 loads — maximal MLP, 16 B/lane coalescing.
    float4 d[3][4];
    #pragma unroll
    for (int k = 0; k < 4; ++k) {
        const int idx4 = k * 64 + lane;
        const bool ok = idx4 < NF4;     // k<3 always ok; k==3 needs lane<58
        d[0][k] = ok ? r0[idx4] : pad;
        d[1][k] = ok ? r1[idx4] : pad;
        d[2][k] = ok ? r2[idx4] : pad;
    }

    int t = t0;
    #pragma unroll
    for (int s = 0; s < 3; ++s) {
        int nt;
        if (t < 0 || t >= NCLASS) {     // wave-uniform branch
            nt = IGNORE_INDEX;
        } else {
            // Broadcast v = x[t]: uniform select (compile-time indices) + shfl.
            const int idx4 = t >> 2;
            const int lane_src = idx4 & 63;
            const int kt = idx4 >> 6;
            const int et = t & 3;
            const float4 dk = (kt == 0) ? d[s][0]
                            : (kt == 1) ? d[s][1]
                            : (kt == 2) ? d[s][2] : d[s][3];
            const float cand = (et == 0) ? dk.x
                             : (et == 1) ? dk.y
                             : (et == 2) ? dk.z : dk.w;
            const float v = __shfl(cand, lane_src, 64);

            int cnt = 0;
            #pragma unroll
            for (int k = 0; k < 4; ++k) {
                const int jb = (k * 64 + lane) * 4;
                const float4 q = d[s][k];
                cnt += (q.x > v) || (q.x == v && (jb + 0) < t);
                cnt += (q.y > v) || (q.y == v && (jb + 1) < t);
                cnt += (q.z > v) || (q.z == v && (jb + 2) < t);
                cnt += (q.w > v) || (q.w == v && (jb + 3) < t);
            }
            // 64-lane butterfly: every lane ends with the full rank.
            #pragma unroll
            for (int off = 32; off > 0; off >>= 1)
                cnt += __shfl_xor(cnt, off, 64);
            nt = cnt;
        }
        t = nt;
        if (lane == 0) out[(s + 1) * BROWS + row] = t;
    }
}

extern "C" void kernel_launch(void* const* d_in, const int* in_sizes, int n_in,
                              void* d_out, int out_size, void* d_ws, size_t ws_size,
                              hipStream_t stream) {
    const float* x0     = (const float*)d_in[0];
    const float* x1     = (const float*)d_in[1];
    const float* x2     = (const float*)d_in[2];
    // d_in[3] (x3) is never used by the reference's outputs.
    const int*   target = (const int*)d_in[4];
    int*         out    = (int*)d_out;

    const int waves_per_block = 256 / 64;
    const int grid = (BROWS + waves_per_block - 1) / waves_per_block;
    TopKBaseLoss_80281528697452_kernel<<<grid, 256, 0, stream>>>(x0, x1, x2, target, out);
}

// Round 3
// 35.757 us; speedup vs baseline: 2.8117x; 2.8117x over previous
//
#include <hip/hip_runtime.h>
#include <math.h>

#define BROWS 16384
#define NCLASS 1000
#define NF4 250            // float4 chunks per row (1000/4)
#define IGNORE_INDEX (-100)

// rank(t) = #{j: p[j] > p[t]} + #{j: p[j] == p[t] && j < t}
// q0..q3 are this lane's four float4 chunks of the row (chunk k holds
// classes [(k*64+lane)*4, +4)). t is wave-uniform and in [0, NCLASS).
// All operands are NAMED registers — no arrays, nothing the register
// allocator can demote to scratch (R2's 213 MB spill lesson).
__device__ __forceinline__ int rank_stage(float4 q0, float4 q1, float4 q2, float4 q3,
                                          int t, int lane)
{
    // Broadcast v = x[t]: dynamic register select (v_cndmask chain) + shfl.
    const int idx4     = t >> 2;
    const int lane_src = idx4 & 63;
    const int kt       = idx4 >> 6;   // which chunk
    const int et       = t & 3;       // which element
    const float4 dk  = (kt == 0) ? q0 : (kt == 1) ? q1 : (kt == 2) ? q2 : q3;
    const float cand = (et == 0) ? dk.x : (et == 1) ? dk.y : (et == 2) ? dk.z : dk.w;
    const float v = __shfl(cand, lane_src, 64);

    const int j0 = (lane)       * 4;
    const int j1 = (64  + lane) * 4;
    const int j2 = (128 + lane) * 4;
    const int j3 = (192 + lane) * 4;

    int cnt = 0;
#define CNT4(Q, JB)                                          \
    cnt += ((Q).x > v) || ((Q).x == v && ((JB) + 0) < t);    \
    cnt += ((Q).y > v) || ((Q).y == v && ((JB) + 1) < t);    \
    cnt += ((Q).z > v) || ((Q).z == v && ((JB) + 2) < t);    \
    cnt += ((Q).w > v) || ((Q).w == v && ((JB) + 3) < t);
    CNT4(q0, j0) CNT4(q1, j1) CNT4(q2, j2) CNT4(q3, j3)
#undef CNT4

    // 64-lane butterfly: every lane ends with the full rank.
    #pragma unroll
    for (int off = 32; off > 0; off >>= 1)
        cnt += __shfl_xor(cnt, off, 64);
    return cnt;
}

__global__ __launch_bounds__(256) void TopKBaseLoss_80281528697452_kernel(
    const float* __restrict__ x0,
    const float* __restrict__ x1,
    const float* __restrict__ x2,
    const int*   __restrict__ target,
    int*         __restrict__ out)
{
    const int gid  = blockIdx.x * blockDim.x + threadIdx.x;
    const int row  = gid >> 6;          // one wave per row
    const int lane = threadIdx.x & 63;
    if (row >= BROWS) return;

    const int t0 = target[row];         // uniform across the wave
    if (lane == 0) out[row] = t0;       // output 0: the original target

    const float4* __restrict__ r0 = (const float4*)(x0 + (long)row * NCLASS);
    const float4* __restrict__ r1 = (const float4*)(x1 + (long)row * NCLASS);
    const float4* __restrict__ r2 = (const float4*)(x2 + (long)row * NCLASS);

    const float NEG = -INFINITY;        // pad can never count: v is finite
    const float4 pad = make_float4(NEG, NEG, NEG, NEG);

    const int i0 = lane, i1 = 64 + lane, i2 = 128 + lane, i3 = 192 + lane;
    const bool ok3 = (i3 < NF4);        // lane < 58

    // 12 independent dwordx4 loads into NAMED registers — max MLP, no arrays.
    float4 a0 = r0[i0], a1 = r0[i1], a2 = r0[i2], a3 = ok3 ? r0[i3] : pad;
    float4 b0 = r1[i0], b1 = r1[i1], b2 = r1[i2], b3 = ok3 ? r1[i3] : pad;
    float4 c0 = r2[i0], c1 = r2[i1], c2 = r2[i2], c3 = ok3 ? r2[i3] : pad;

    int t = t0;

    if (t >= 0 && t < NCLASS) t = rank_stage(a0, a1, a2, a3, t, lane);
    else                      t = IGNORE_INDEX;
    if (lane == 0) out[BROWS + row] = t;

    if (t >= 0 && t < NCLASS) t = rank_stage(b0, b1, b2, b3, t, lane);
    else                      t = IGNORE_INDEX;
    if (lane == 0) out[2 * BROWS + row] = t;

    if (t >= 0 && t < NCLASS) t = rank_stage(c0, c1, c2, c3, t, lane);
    else                      t = IGNORE_INDEX;
    if (lane == 0) out[3 * BROWS + row] = t;
}

extern "C" void kernel_launch(void* const* d_in, const int* in_sizes, int n_in,
                              void* d_out, int out_size, void* d_ws, size_t ws_size,
                              hipStream_t stream) {
    const float* x0     = (const float*)d_in[0];
    const float* x1     = (const float*)d_in[1];
    const float* x2     = (const float*)d_in[2];
    // d_in[3] (x3) is never used by the reference's outputs.
    const int*   target = (const int*)d_in[4];
    int*         out    = (int*)d_out;

    const int waves_per_block = 256 / 64;
    const int grid = (BROWS + waves_per_block - 1) / waves_per_block;
    TopKBaseLoss_80281528697452_kernel<<<grid, 256, 0, stream>>>(x0, x1, x2, target, out);
}

// Round 4
// 35.478 us; speedup vs baseline: 2.8338x; 1.0079x over previous
//
#include <hip/hip_runtime.h>
#include <math.h>

#define BROWS 16384
#define NCLASS 1000
#define NF4 250            // float4 chunks per row (1000/4)
#define IGNORE_INDEX (-100)

// rank(t) = #{j: p[j] > p[t]} + #{j: p[j] == p[t] && j < t}
// Reduction via ballot+popcount: for each of the 16 element positions this
// lane owns, one wave-wide __ballot + scalar popcount-accumulate. No 6-deep
// shfl butterfly; result is wave-uniform by construction (t stays scalar).
__device__ __forceinline__ int rank_stage(float4 q0, float4 q1, float4 q2, float4 q3,
                                          int t, int lane)
{
    // Broadcast v = x[t]: dynamic register select (v_cndmask chain) + shfl.
    const int idx4     = t >> 2;
    const int lane_src = idx4 & 63;
    const int kt       = idx4 >> 6;   // which chunk
    const int et       = t & 3;       // which element
    const float4 dk  = (kt == 0) ? q0 : (kt == 1) ? q1 : (kt == 2) ? q2 : q3;
    const float cand = (et == 0) ? dk.x : (et == 1) ? dk.y : (et == 2) ? dk.z : dk.w;
    const float v = __shfl(cand, lane_src, 64);

    const int j0 = (lane)       * 4;
    const int j1 = (64  + lane) * 4;
    const int j2 = (128 + lane) * 4;
    const int j3 = (192 + lane) * 4;

    int cnt = 0;
#define BAL(Q, C, JB, OFS)                                                     \
    cnt += __popcll(__ballot(((Q).C > v) || ((Q).C == v && ((JB)+(OFS)) < t)));
    BAL(q0, x, j0, 0) BAL(q0, y, j0, 1) BAL(q0, z, j0, 2) BAL(q0, w, j0, 3)
    BAL(q1, x, j1, 0) BAL(q1, y, j1, 1) BAL(q1, z, j1, 2) BAL(q1, w, j1, 3)
    BAL(q2, x, j2, 0) BAL(q2, y, j2, 1) BAL(q2, z, j2, 2) BAL(q2, w, j2, 3)
    BAL(q3, x, j3, 0) BAL(q3, y, j3, 1) BAL(q3, z, j3, 2) BAL(q3, w, j3, 3)
#undef BAL
    return cnt;   // identical in every lane
}

__global__ __launch_bounds__(256) void TopKBaseLoss_80281528697452_kernel(
    const float* __restrict__ x0,
    const float* __restrict__ x1,
    const float* __restrict__ x2,
    const int*   __restrict__ target,
    int*         __restrict__ out)
{
    const int gid  = blockIdx.x * blockDim.x + threadIdx.x;
    const int row  = gid >> 6;          // one wave per row (grid covers exactly)
    const int lane = threadIdx.x & 63;
    if (row >= BROWS) return;

    const int t0 = target[row];         // uniform across the wave
    if (lane == 0) out[row] = t0;       // output 0: the original target

    const float4* __restrict__ r0 = (const float4*)(x0 + (long)row * NCLASS);
    const float4* __restrict__ r1 = (const float4*)(x1 + (long)row * NCLASS);
    const float4* __restrict__ r2 = (const float4*)(x2 + (long)row * NCLASS);

    const float NEG = -INFINITY;        // pad can never count: v is finite
    const float4 pad = make_float4(NEG, NEG, NEG, NEG);

    const int i0 = lane, i1 = 64 + lane, i2 = 128 + lane, i3 = 192 + lane;
    const bool ok3 = (i3 < NF4);        // lane < 58

    // 12 independent dwordx4 loads into NAMED registers — max MLP.
    float4 a0 = r0[i0], a1 = r0[i1], a2 = r0[i2], a3 = ok3 ? r0[i3] : pad;
    float4 b0 = r1[i0], b1 = r1[i1], b2 = r1[i2], b3 = ok3 ? r1[i3] : pad;
    float4 c0 = r2[i0], c1 = r2[i1], c2 = r2[i2], c3 = ok3 ? r2[i3] : pad;

    // Forbid the scheduler from sinking the b/c loads below stage-0 compute
    // (R3: compiler chose VGPR=32 and serialized the three load bursts).
    __builtin_amdgcn_sched_barrier(0);

    int t = t0;

    if (t >= 0 && t < NCLASS) t = rank_stage(a0, a1, a2, a3, t, lane);
    else                      t = IGNORE_INDEX;
    if (lane == 0) out[BROWS + row] = t;

    if (t >= 0 && t < NCLASS) t = rank_stage(b0, b1, b2, b3, t, lane);
    else                      t = IGNORE_INDEX;
    if (lane == 0) out[2 * BROWS + row] = t;

    if (t >= 0 && t < NCLASS) t = rank_stage(c0, c1, c2, c3, t, lane);
    else                      t = IGNORE_INDEX;
    if (lane == 0) out[3 * BROWS + row] = t;
}

extern "C" void kernel_launch(void* const* d_in, const int* in_sizes, int n_in,
                              void* d_out, int out_size, void* d_ws, size_t ws_size,
                              hipStream_t stream) {
    const float* x0     = (const float*)d_in[0];
    const float* x1     = (const float*)d_in[1];
    const float* x2     = (const float*)d_in[2];
    // d_in[3] (x3) is never used by the reference's outputs.
    const int*   target = (const int*)d_in[4];
    int*         out    = (int*)d_out;

    const int waves_per_block = 256 / 64;
    const int grid = (BROWS + waves_per_block - 1) / waves_per_block;
    TopKBaseLoss_80281528697452_kernel<<<grid, 256, 0, stream>>>(x0, x1, x2, target, out);
}

// Round 5
// 34.731 us; speedup vs baseline: 2.8948x; 1.0215x over previous
//
#include <hip/hip_runtime.h>
#include <math.h>

#define BROWS 16384
#define NCLASS 1000
#define NF4 250            // float4 chunks per row (1000/4)
#define IGNORE_INDEX (-100)

// Branchless: t_s must already be clamped to [0, NCLASS). Uniform (SGPR).
// Broadcast x[t] = dynamic register select + v_readlane (no DS op).
__device__ __forceinline__ float bcast_val(float4 q0, float4 q1, float4 q2, float4 q3,
                                           int t_s)
{
    const int idx4     = t_s >> 2;
    const int lane_src = idx4 & 63;
    const int kt       = idx4 >> 6;   // which chunk
    const int et       = t_s & 3;     // which element
    const float4 dk  = (kt == 0) ? q0 : (kt == 1) ? q1 : (kt == 2) ? q2 : q3;
    const float cand = (et == 0) ? dk.x : (et == 1) ? dk.y : (et == 2) ? dk.z : dk.w;
    return __int_as_float(__builtin_amdgcn_readlane(__float_as_int(cand), lane_src));
}

// rank(t) = #{j: p[j] > p[t]} + #{j: p[j] == p[t] && j < t}, via 16
// ballot+popcount (no shfl butterfly; result uniform by construction).
// Fully branchless: out-of-range t folds to IGNORE via a scalar select.
__device__ __forceinline__ int rank_stage(float4 q0, float4 q1, float4 q2, float4 q3,
                                          int t, int lane)
{
    const bool tin = (t >= 0) && (t < NCLASS);   // wave-uniform
    const int  tc  = tin ? t : 0;                // clamped, safe everywhere
    const float v  = bcast_val(q0, q1, q2, q3, tc);

    const int j0 = (lane)       * 4;
    const int j1 = (64  + lane) * 4;
    const int j2 = (128 + lane) * 4;
    const int j3 = (192 + lane) * 4;

    int cnt = 0;
#define BAL(Q, C, JB, OFS)                                                      \
    cnt += __popcll(__ballot(((Q).C > v) || ((Q).C == v && ((JB)+(OFS)) < tc)));
    BAL(q0, x, j0, 0) BAL(q0, y, j0, 1) BAL(q0, z, j0, 2) BAL(q0, w, j0, 3)
    BAL(q1, x, j1, 0) BAL(q1, y, j1, 1) BAL(q1, z, j1, 2) BAL(q1, w, j1, 3)
    BAL(q2, x, j2, 0) BAL(q2, y, j2, 1) BAL(q2, z, j2, 2) BAL(q2, w, j2, 3)
    BAL(q3, x, j3, 0) BAL(q3, y, j3, 1) BAL(q3, z, j3, 2) BAL(q3, w, j3, 3)
#undef BAL
    return tin ? cnt : IGNORE_INDEX;             // scalar select, no branch
}

__global__ __launch_bounds__(256) void TopKBaseLoss_80281528697452_kernel(
    const float* __restrict__ x0,
    const float* __restrict__ x1,
    const float* __restrict__ x2,
    const int*   __restrict__ target,
    int*         __restrict__ out)
{
    // Grid covers exactly BROWS waves — no bounds check, no early-return
    // block, so MachineSink has no downstream block to sink loads into
    // (R4 lesson: sched_barrier can't stop cross-block sinking).
    const int row  = blockIdx.x * 4 + (threadIdx.x >> 6);
    const int lane = threadIdx.x & 63;

    const int t0 = __builtin_amdgcn_readfirstlane(target[row]);  // uniform SGPR

    const float4* __restrict__ r0 = (const float4*)(x0 + (long)row * NCLASS);
    const float4* __restrict__ r1 = (const float4*)(x1 + (long)row * NCLASS);
    const float4* __restrict__ r2 = (const float4*)(x2 + (long)row * NCLASS);

    const float NEG = -INFINITY;        // pad can never count: v is finite
    const float4 pad = make_float4(NEG, NEG, NEG, NEG);

    const int i0 = lane, i1 = 64 + lane, i2 = 128 + lane;
    const int i3 = 192 + lane;
    const bool ok3 = (i3 < NF4);        // lane < 58
    const int i3c = ok3 ? i3 : (NF4 - 1);   // clamped ADDRESS — always in
                                            // bounds, value cndmask'd below
                                            // (no exec-masked load region)

    // 12 independent dwordx4 loads into NAMED registers — max MLP.
    float4 a0 = r0[i0], a1 = r0[i1], a2 = r0[i2], a3t = r0[i3c];
    float4 b0 = r1[i0], b1 = r1[i1], b2 = r1[i2], b3t = r1[i3c];
    float4 c0 = r2[i0], c1 = r2[i1], c2 = r2[i2], c3t = r2[i3c];
    const float4 a3 = ok3 ? a3t : pad;
    const float4 b3 = ok3 ? b3t : pad;
    const float4 c3 = ok3 ? c3t : pad;

    // Keep all 12 loads issued before any stage compute.
    __builtin_amdgcn_sched_barrier(0);

    const int t1 = rank_stage(a0, a1, a2, a3, t0, lane);
    const int t2 = rank_stage(b0, b1, b2, b3, t1, lane);
    const int t3 = rank_stage(c0, c1, c2, c3, t2, lane);

    // Single divergent region at the very end.
    if (lane == 0) {
        out[row]             = t0;
        out[BROWS + row]     = t1;
        out[2 * BROWS + row] = t2;
        out[3 * BROWS + row] = t3;
    }
}

extern "C" void kernel_launch(void* const* d_in, const int* in_sizes, int n_in,
                              void* d_out, int out_size, void* d_ws, size_t ws_size,
                              hipStream_t stream) {
    const float* x0     = (const float*)d_in[0];
    const float* x1     = (const float*)d_in[1];
    const float* x2     = (const float*)d_in[2];
    // d_in[3] (x3) is never used by the reference's outputs.
    const int*   target = (const int*)d_in[4];
    int*         out    = (int*)d_out;

    const int grid = BROWS / 4;         // 4 waves (rows) per 256-thread block
    TopKBaseLoss_80281528697452_kernel<<<grid, 256, 0, stream>>>(x0, x1, x2, target, out);
}